// Round 3
// baseline (434.822 us; speedup 1.0000x reference)
//
#include <hip/hip_runtime.h>
#include <hip/hip_bf16.h>
#include <math.h>

#define T_NCE 0.07f
#define EPSF 1e-7f

// ---------------- workspace layout (float units) ----------------
// [0]  : dtype flag (int; 1 = bf16 inputs, 0 = f32 inputs)
// [8]  : acc loss_cls   [9] : acc loss_rel
// [10] : acc loss_act   [11]: acc snico sum
// WS_MEANS : 4*64*2048 per-batch channel SUMS (not means; scale cancels in NCE)
// WS_DOTS  : 2*64*150 raw dots   WS_NSQ : 2*64*150 row sumsq
#define WS_MEANS 32
#define MEANS_N (4 * 64 * 2048)
#define WS_DOTS (WS_MEANS + MEANS_N)
#define WS_NSQ  (WS_DOTS + 2 * 64 * 150)

__device__ __forceinline__ float bf2f(unsigned short h) {
    unsigned int u = ((unsigned int)h) << 16;
    float f;
    __builtin_memcpy(&f, &u, 4);
    return f;
}

__device__ __forceinline__ float ldf(const void* p, int i, int bf) {
    if (bf) return bf2f(((const unsigned short*)p)[i]);
    return ((const float*)p)[i];
}

struct F8 { float v[8]; };

__device__ __forceinline__ F8 ld8(const void* p, int i, int bf) {
    F8 r;
    if (bf) {
        uint4 u = *((const uint4*)((const unsigned short*)p + i));
        const unsigned short* hs = (const unsigned short*)&u;
#pragma unroll
        for (int k = 0; k < 8; k++) r.v[k] = bf2f(hs[k]);
    } else {
        const float4* q = (const float4*)((const float*)p + i);
        float4 a = q[0], b = q[1];
        r.v[0] = a.x; r.v[1] = a.y; r.v[2] = a.z; r.v[3] = a.w;
        r.v[4] = b.x; r.v[5] = b.y; r.v[6] = b.z; r.v[7] = b.w;
    }
    return r;
}

__device__ __forceinline__ float block_reduce256(float v, float* sbuf) {
    int t = threadIdx.x;
    sbuf[t] = v;
    __syncthreads();
    for (int s = 128; s > 0; s >>= 1) {
        if (t < s) sbuf[t] += sbuf[t + s];
        __syncthreads();
    }
    float r = sbuf[0];
    __syncthreads();
    return r;
}

__device__ __forceinline__ float block_reduce_max256(float v, float* sbuf) {
    int t = threadIdx.x;
    sbuf[t] = v;
    __syncthreads();
    for (int s = 128; s > 0; s >>= 1) {
        if (t < s) sbuf[t] = fmaxf(sbuf[t], sbuf[t + s]);
        __syncthreads();
    }
    float r = sbuf[0];
    __syncthreads();
    return r;
}

// ---------------- kernel 1: probe dtype + zero the 4 loss accumulators -----
__global__ void k_zero(const void* video_scores, float* ws) {
    if (threadIdx.x == 0) {
        const unsigned short* u = (const unsigned short*)video_scores;
        int cnt = 0;
        for (int i = 0; i < 64; i++) {
            unsigned short h = u[2 * i];
            int e = (h >> 7) & 0xFF;
            int sgn = (h >> 15) & 1;
            if (!sgn && e >= 90 && e <= 126) cnt++;
        }
        ((int*)ws)[0] = (cnt >= 56) ? 1 : 0;
        ws[8] = 0.f; ws[9] = 0.f; ws[10] = 0.f; ws[11] = 0.f;
    }
}

// ---------------- kernel 2: per-batch channel sums of HA/EA/HB/EB -----------
// grid 256 = arr(4) * b(64); block 1024 = 16 waves.
// Thread t: ct = t&255 covers channels ct*8..ct*8+7 (16 B); g = t>>8 is the
// row-group, rows g, g+4, g+8, ... Block streams its 600 KB (arr,b) slab
// front-to-back CONTIGUOUSLY (4 consecutive rows = 16 KB per step), with an
// explicit 8-deep raw-load pipeline (old version: strided 1KB/4KB comb +
// VGPR=32 -> ~1 load in flight -> 1.38 TB/s, VALUBusy 2.2%).
// Cross-row-group combine via LDS; plain stores; no atomics.
__global__ __launch_bounds__(1024) void k_means(const void* HA, const void* EA,
                                                const void* HB, const void* EB,
                                                float* ws) {
    int bf = ((const int*)ws)[0];
    __shared__ float part[4][2048];
    int bi = blockIdx.x;
    int b = bi & 63;
    int arr = bi >> 6;
    const void* src = (arr == 0) ? HA : (arr == 1) ? EA : (arr == 2) ? HB : EB;
    int t = threadIdx.x;
    int ct = t & 255;
    int g = t >> 8;               // wave-uniform (64 consecutive threads share g)
    int base = b * 150 * 2048 + ct * 8;

    float acc[8];
#pragma unroll
    for (int e = 0; e < 8; e++) acc[e] = 0.f;

    if (bf) {
        const unsigned short* sp = (const unsigned short*)src;
        int j = g;
        // rows per group: 37-38; 5 batches x 8 = 40 slots, tail guarded
        for (int batch = 0; batch < 5; batch++) {
            uint4 r[8];
#pragma unroll
            for (int k = 0; k < 8; k++) {
                int jj = j + 4 * k;
                if (jj < 150) r[k] = *(const uint4*)(sp + base + jj * 2048);
            }
#pragma unroll
            for (int k = 0; k < 8; k++) {
                int jj = j + 4 * k;
                if (jj < 150) {
                    const unsigned short* hs = (const unsigned short*)&r[k];
#pragma unroll
                    for (int e = 0; e < 8; e++) acc[e] += bf2f(hs[e]);
                }
            }
            j += 32;
        }
    } else {
        const float* fp = (const float*)src;
        int j = g;
        for (int batch = 0; batch < 10; batch++) {
            float4 r[4][2];
#pragma unroll
            for (int k = 0; k < 4; k++) {
                int jj = j + 4 * k;
                if (jj < 150) {
                    const float4* p = (const float4*)(fp + base + jj * 2048);
                    r[k][0] = p[0];
                    r[k][1] = p[1];
                }
            }
#pragma unroll
            for (int k = 0; k < 4; k++) {
                int jj = j + 4 * k;
                if (jj < 150) {
                    acc[0] += r[k][0].x; acc[1] += r[k][0].y;
                    acc[2] += r[k][0].z; acc[3] += r[k][0].w;
                    acc[4] += r[k][1].x; acc[5] += r[k][1].y;
                    acc[6] += r[k][1].z; acc[7] += r[k][1].w;
                }
            }
            j += 16;
        }
    }

#pragma unroll
    for (int e = 0; e < 8; e++) part[g][ct * 8 + e] = acc[e];
    __syncthreads();

    float* dst = ws + WS_MEANS + (arr * 64 + b) * 2048;
    for (int c = t; c < 2048; c += 1024)
        dst[c] = part[0][c] + part[1][c] + part[2][c] + part[3][c];
}

// ---------------- kernel 3: raw dots q.neg_row + row sumsq ------------------
// grid 1920 = which(2) * b(64) * chunk(15 of 10 rows); block 256 = 4 waves.
// q fragment in 32 registers per lane. bf16 path loads TWO full rows raw
// (8 x 16 B in flight) before converting/accumulating.
__device__ __forceinline__ void dotrow_bf(const uint4* r, const float* qreg,
                                          float& dot, float& nsq) {
#pragma unroll
    for (int it = 0; it < 4; it++) {
        const unsigned short* hs = (const unsigned short*)&r[it];
#pragma unroll
        for (int k = 0; k < 8; k++) {
            float x = bf2f(hs[k]);
            dot += x * qreg[it * 8 + k];
            nsq += x * x;
        }
    }
}

__global__ void k_dots(const void* EA, const void* EB, float* ws) {
    int bf = ((const int*)ws)[0];
    int bi = blockIdx.x;
    int which = bi / 960;
    int rem = bi % 960;
    int b = rem / 15;
    int chunk = rem % 15;
    int lane = threadIdx.x & 63;
    int wid = threadIdx.x >> 6;

    const float* qb = ws + WS_MEANS + ((which == 0 ? 0 : 2) * 64 + b) * 2048;
    float qreg[32];
#pragma unroll
    for (int it = 0; it < 4; it++) {
        const float4* p = (const float4*)(qb + it * 512 + lane * 8);
        float4 a = p[0], c = p[1];
        qreg[it * 8 + 0] = a.x; qreg[it * 8 + 1] = a.y;
        qreg[it * 8 + 2] = a.z; qreg[it * 8 + 3] = a.w;
        qreg[it * 8 + 4] = c.x; qreg[it * 8 + 5] = c.y;
        qreg[it * 8 + 6] = c.z; qreg[it * 8 + 7] = c.w;
    }

    const void* neg = (which == 0) ? EB : EA;
    int e0 = chunk * 10;
    int outb = WS_DOTS + (which * 64 + b) * 150;
    int nsqb = WS_NSQ + (which * 64 + b) * 150;

    if (bf) {
        const unsigned short* np = (const unsigned short*)neg;
        int jA = e0 + wid;          // always < e0+10
        int jB = jA + 4;            // always < e0+10
        int jC = jA + 8;            // valid iff wid < 2 (wave-uniform)
        uint4 rA[4], rB[4];
#pragma unroll
        for (int it = 0; it < 4; it++)
            rA[it] = *(const uint4*)(np + (b * 150 + jA) * 2048 + it * 512 + lane * 8);
#pragma unroll
        for (int it = 0; it < 4; it++)
            rB[it] = *(const uint4*)(np + (b * 150 + jB) * 2048 + it * 512 + lane * 8);
        float dA = 0.f, nA = 0.f, dB = 0.f, nB = 0.f;
        dotrow_bf(rA, qreg, dA, nA);
        dotrow_bf(rB, qreg, dB, nB);
        for (int s = 32; s > 0; s >>= 1) {
            dA += __shfl_down(dA, s); nA += __shfl_down(nA, s);
            dB += __shfl_down(dB, s); nB += __shfl_down(nB, s);
        }
        if (lane == 0) {
            ws[outb + jA] = dA; ws[nsqb + jA] = nA;
            ws[outb + jB] = dB; ws[nsqb + jB] = nB;
        }
        if (jC < e0 + 10) {
            uint4 rC[4];
#pragma unroll
            for (int it = 0; it < 4; it++)
                rC[it] = *(const uint4*)(np + (b * 150 + jC) * 2048 + it * 512 + lane * 8);
            float dC = 0.f, nC = 0.f;
            dotrow_bf(rC, qreg, dC, nC);
            for (int s = 32; s > 0; s >>= 1) {
                dC += __shfl_down(dC, s); nC += __shfl_down(nC, s);
            }
            if (lane == 0) {
                ws[outb + jC] = dC; ws[nsqb + jC] = nC;
            }
        }
    } else {
        for (int j = e0 + wid; j < e0 + 10; j += 4) {
            int base = (b * 150 + j) * 2048;
            float dot = 0.f, nsq = 0.f;
#pragma unroll
            for (int it = 0; it < 4; it++) {
                int off = it * 512 + lane * 8;
                F8 v = ld8(neg, base + off, 0);
#pragma unroll
                for (int k = 0; k < 8; k++) {
                    float x = v.v[k];
                    dot += x * qreg[it * 8 + k];
                    nsq += x * x;
                }
            }
            for (int s = 32; s > 0; s >>= 1) {
                dot += __shfl_down(dot, s);
                nsq += __shfl_down(nsq, s);
            }
            if (lane == 0) {
                ws[outb + j] = dot;
                ws[nsqb + j] = nsq;
            }
        }
    }
}

// ---------------- kernel 4: fused cls + rel + act ---------------------------
// grid 66: block 0 = cls; blocks 1..32 = rel + act-part2; blocks 33..65 = act-part1
__global__ void k_small(const void* vs, const void* label,
                        const void* res, const void* red,
                        const void* a0, const void* a2, float* ws) {
    int bf = ((const int*)ws)[0];
    __shared__ float sbuf[256];
    __shared__ float rowsum[64];
    __shared__ float sa0[64 * 40];
    __shared__ float sa2[64 * 40];
    int t = threadIdx.x;
    int bi = blockIdx.x;

    if (bi == 0) {
        // ---- loss_cls ----
        if (t < 64) {
            float s = 0.f;
            for (int c = 0; c < 20; c++) s += ldf(label, t * 20 + c, bf);
            rowsum[t] = s;
        }
        __syncthreads();
        float local = 0.f;
        for (int i = t; i < 1280; i += 256) {
            int b = i / 20;
            float lab = ldf(label, i, bf) / rowsum[b];
            float v = ldf(vs, i, bf);
            v = fminf(fmaxf(v, EPSF), 1.f - EPSF);
            local += lab * logf(v) + (1.f - lab) * log1pf(-v);
        }
        float s = block_reduce256(local, sbuf);
        if (t == 0) ws[8] = -s / 1280.f;
    } else if (bi <= 32) {
        // ---- loss_rel + act part2 ----
        int base = (bi - 1) * 256 + t;
        int stride = 32 * 256;
        float lrel = 0.f;
        for (int i = base; i < 96000; i += stride) {
            float sv = ldf(res, i, bf);
            float dv = ldf(red, i, bf);
            lrel += (1.f - sv) * (1.f - sv) + dv * dv;
        }
        float s = block_reduce256(lrel, sbuf);
        if (t == 0) atomicAdd(&ws[9], s * (1.f / 96000.f));
        float lact = 0.f;
        for (int i = base; i < 48000; i += stride) {
            float x = ldf(a0, i, bf) - ldf(a2, i, bf);
            lact += x * x;
        }
        s = block_reduce256(lact, sbuf);
        if (t == 0) atomicAdd(&ws[10], s * (0.1f / 64.f));
    } else {
        // ---- act part1: 750x11 windows, sum over batch; LDS staging ----
        int abi = bi - 33;
        int B0 = abi * 256;
        int B1 = min(B0 + 255, 8249);
        int tmin = B0 / 11, tmax = B1 / 11;
        int lo = max(0, tmin - 6);
        int hi = min(749, tmax + 5);
        int ncol = hi - lo + 1;  // <= 36
        int total = 64 * ncol;
        for (int i = t; i < total; i += 256) {
            int b = i / ncol;
            int col = i % ncol;
            sa0[i] = ldf(a0, b * 750 + lo + col, bf);
            sa2[i] = ldf(a2, b * 750 + lo + col, bf);
        }
        __syncthreads();
        int id = B0 + t;
        float val = 0.f;
        if (id < 8250) {
            int tt = id / 11;
            int d = id % 11;
            int c = min(max(tt + d - 6, 0), 749);
            int ct = tt - lo, cc = c - lo;
            float wsum = 0.f, asum = 0.f;
            for (int b = 0; b < 64; b++) {
                float x = sa0[b * ncol + ct];
                float y = sa0[b * ncol + cc];
                wsum += (x - y) * (x - y);
                float p = sa2[b * ncol + ct];
                float q = sa2[b * ncol + cc];
                asum += fabsf(p - q);
            }
            val = __expf(-0.5f * wsum) * (asum * (1.f / 64.f));
        }
        float s = block_reduce256(val, sbuf);
        if (t == 0) atomicAdd(&ws[10], s);
    }
}

// ---------------- kernel 5: NCE norms + logsumexp per (which,b) -------------
// grid 128; block 256
__global__ void k_nce(const void* att, float* ws) {
    int bf = ((const int*)ws)[0];
    __shared__ float sbuf[256];
    int t = threadIdx.x;
    int w = blockIdx.x >> 6;
    int b = blockIdx.x & 63;
    const float* qv = ws + WS_MEANS + ((w == 0 ? 0 : 2) * 64 + b) * 2048;
    const float* kv = ws + WS_MEANS + ((w == 0 ? 1 : 3) * 64 + b) * 2048;
    float p0 = 0.f, p1 = 0.f, p2 = 0.f;
    for (int c = t; c < 2048; c += 256) {
        float qa = qv[c], ka = kv[c];
        p0 += qa * qa; p1 += ka * ka; p2 += qa * ka;
    }
    float nq = block_reduce256(p0, sbuf);
    float nk = block_reduce256(p1, sbuf);
    float dd = block_reduce256(p2, sbuf);
    float invq = rsqrtf(nq);
    float lpos = dd * invq * rsqrtf(nk) * (1.f / T_NCE);
    float lg = -INFINITY;
    if (t < 150) {
        float raw = ws[WS_DOTS + (w * 64 + b) * 150 + t];
        float nn = ws[WS_NSQ + (w * 64 + b) * 150 + t];
        float a = ldf(att, b * 300 + w * 150 + t, bf);
        lg = a * raw * invq * rsqrtf(nn) * (1.f / T_NCE);
    }
    float m = block_reduce_max256(lg, sbuf);
    m = fmaxf(m, lpos);
    float ex = (t < 150) ? expf(lg - m) : 0.f;
    float ssum = block_reduce256(ex, sbuf) + expf(lpos - m);
    if (t == 0) {
        float loss = (m + logf(ssum)) - lpos;  // -log_softmax[0]
        atomicAdd(&ws[11], loss * (1.f / 64.f));
    }
}

// ---------------- kernel 6: final combine -----------------------------------
__global__ void k_out(float* ws, void* out) {
    if (threadIdx.x == 0) {
        int bf = ((const int*)ws)[0];
        float cls = ws[8], rel = ws[9], act = ws[10], snico = ws[11];
        float total = cls + 0.01f * snico + act + 0.1f * rel;
        if (bf) {
            __hip_bfloat16* o = (__hip_bfloat16*)out;
            o[0] = __float2bfloat16(total);
            o[1] = __float2bfloat16(cls);
            o[2] = __float2bfloat16(snico);
            o[3] = __float2bfloat16(act);
            o[4] = __float2bfloat16(rel);
        } else {
            float* o = (float*)out;
            o[0] = total; o[1] = cls; o[2] = snico; o[3] = act; o[4] = rel;
        }
    }
}

extern "C" void kernel_launch(void* const* d_in, const int* in_sizes, int n_in,
                              void* d_out, int out_size, void* d_ws, size_t ws_size,
                              hipStream_t stream) {
    const void* video_scores = d_in[0];
    const void* label = d_in[1];
    const void* HA = d_in[2];
    const void* EA = d_in[3];
    const void* HB = d_in[4];
    const void* EB = d_in[5];
    const void* re_s = d_in[6];
    const void* re_d = d_in[7];
    const void* actioness = d_in[8];
    const void* actioness_2 = d_in[9];
    const void* att = d_in[10];
    float* ws = (float*)d_ws;

    k_zero<<<1, 64, 0, stream>>>(video_scores, ws);
    k_means<<<256, 1024, 0, stream>>>(HA, EA, HB, EB, ws);
    k_dots<<<1920, 256, 0, stream>>>(EA, EB, ws);
    k_small<<<66, 256, 0, stream>>>(video_scores, label, re_s, re_d,
                                    actioness, actioness_2, ws);
    k_nce<<<128, 256, 0, stream>>>(att, ws);
    k_out<<<1, 1, 0, stream>>>(ws, d_out);
}

// Round 4
// 348.753 us; speedup vs baseline: 1.2468x; 1.2468x over previous
//
#include <hip/hip_runtime.h>
#include <hip/hip_bf16.h>
#include <math.h>

#define T_NCE 0.07f
#define EPSF 1e-7f

// ---------------- workspace layout (float units) ----------------
// [0]  : dtype flag (int; 1 = bf16 inputs, 0 = f32 inputs)
// [8]  : acc loss_cls   [9] : acc loss_rel
// [10] : acc loss_act   [11]: acc snico sum
// WS_MEANS : 4*64*2048 per-batch channel SUMS (not means; scale cancels in NCE)
// WS_DOTS  : 2*64*150 raw dots   WS_NSQ : 2*64*150 row sumsq
#define WS_MEANS 32
#define MEANS_N (4 * 64 * 2048)
#define WS_DOTS (WS_MEANS + MEANS_N)
#define WS_NSQ  (WS_DOTS + 2 * 64 * 150)

__device__ __forceinline__ float bf2f(unsigned short h) {
    unsigned int u = ((unsigned int)h) << 16;
    float f;
    __builtin_memcpy(&f, &u, 4);
    return f;
}

__device__ __forceinline__ float ldf(const void* p, int i, int bf) {
    if (bf) return bf2f(((const unsigned short*)p)[i]);
    return ((const float*)p)[i];
}

struct F8 { float v[8]; };

__device__ __forceinline__ F8 ld8(const void* p, int i, int bf) {
    F8 r;
    if (bf) {
        uint4 u = *((const uint4*)((const unsigned short*)p + i));
        const unsigned short* hs = (const unsigned short*)&u;
#pragma unroll
        for (int k = 0; k < 8; k++) r.v[k] = bf2f(hs[k]);
    } else {
        const float4* q = (const float4*)((const float*)p + i);
        float4 a = q[0], b = q[1];
        r.v[0] = a.x; r.v[1] = a.y; r.v[2] = a.z; r.v[3] = a.w;
        r.v[4] = b.x; r.v[5] = b.y; r.v[6] = b.z; r.v[7] = b.w;
    }
    return r;
}

__device__ __forceinline__ float block_reduce256(float v, float* sbuf) {
    int t = threadIdx.x;
    sbuf[t] = v;
    __syncthreads();
    for (int s = 128; s > 0; s >>= 1) {
        if (t < s) sbuf[t] += sbuf[t + s];
        __syncthreads();
    }
    float r = sbuf[0];
    __syncthreads();
    return r;
}

__device__ __forceinline__ float block_reduce_max256(float v, float* sbuf) {
    int t = threadIdx.x;
    sbuf[t] = v;
    __syncthreads();
    for (int s = 128; s > 0; s >>= 1) {
        if (t < s) sbuf[t] = fmaxf(sbuf[t], sbuf[t + s]);
        __syncthreads();
    }
    float r = sbuf[0];
    __syncthreads();
    return r;
}

// ---------------- kernel 1: probe dtype + zero the 4 loss accumulators -----
__global__ void k_zero(const void* video_scores, float* ws) {
    if (threadIdx.x == 0) {
        const unsigned short* u = (const unsigned short*)video_scores;
        int cnt = 0;
        for (int i = 0; i < 64; i++) {
            unsigned short h = u[2 * i];
            int e = (h >> 7) & 0xFF;
            int sgn = (h >> 15) & 1;
            if (!sgn && e >= 90 && e <= 126) cnt++;
        }
        ((int*)ws)[0] = (cnt >= 56) ? 1 : 0;
        ws[8] = 0.f; ws[9] = 0.f; ws[10] = 0.f; ws[11] = 0.f;
    }
}

// ---------------- kernel 2: per-batch channel sums of HA/EA/HB/EB -----------
// grid 256 = arr(4) * b(64); block 1024 = 4 row-groups x 256 ch-threads.
// Row split 40/40/40/30 (no remainder): inner loop is n5 iterations of FIVE
// UNCONDITIONAL consecutive-row loads into NAMED registers. R2's version
// guarded each load with `if (jj<150)` -> partially-defined staging arrays ->
// scratch spill (FETCH 154->253 MB, WRITE 2->202 MB at a real 2.4 TB/s stream
// rate). All loads unconditional => no scratch, traffic back to compulsory.
// Cross-group combine via LDS; plain stores; no atomics.
__global__ __launch_bounds__(1024) void k_means(const void* HA, const void* EA,
                                                const void* HB, const void* EB,
                                                float* ws) {
    int bf = ((const int*)ws)[0];
    __shared__ float part[4][2048];
    int bi = blockIdx.x;
    int b = bi & 63;
    int arr = bi >> 6;
    const void* src = (arr == 0) ? HA : (arr == 1) ? EA : (arr == 2) ? HB : EB;
    int t = threadIdx.x;
    int ct = t & 255;
    int g = t >> 8;               // row-group 0..3 (wave-uniform)
    int j0 = g * 40;              // rows [j0, j0+40) for g<3, [120,150) for g=3
    int n5 = (g < 3) ? 8 : 6;     // iterations of 5 rows
    int base = (b * 150 + j0) * 2048 + ct * 8;

    float acc[8];
#pragma unroll
    for (int e = 0; e < 8; e++) acc[e] = 0.f;

    if (bf) {
        const unsigned short* sp = (const unsigned short*)src + base;
        for (int it = 0; it < n5; it++) {
            uint4 r0 = *(const uint4*)(sp);
            uint4 r1 = *(const uint4*)(sp + 2048);
            uint4 r2 = *(const uint4*)(sp + 4096);
            uint4 r3 = *(const uint4*)(sp + 6144);
            uint4 r4 = *(const uint4*)(sp + 8192);
            const unsigned short* h0 = (const unsigned short*)&r0;
            const unsigned short* h1 = (const unsigned short*)&r1;
            const unsigned short* h2 = (const unsigned short*)&r2;
            const unsigned short* h3 = (const unsigned short*)&r3;
            const unsigned short* h4 = (const unsigned short*)&r4;
#pragma unroll
            for (int e = 0; e < 8; e++)
                acc[e] += ((bf2f(h0[e]) + bf2f(h1[e])) +
                           (bf2f(h2[e]) + bf2f(h3[e]))) + bf2f(h4[e]);
            sp += 5 * 2048;
        }
    } else {
        const float* fp = (const float*)src + base;
        for (int it = 0; it < n5; it++) {
            float4 a0 = ((const float4*)(fp))[0];
            float4 b0 = ((const float4*)(fp))[1];
            float4 a1 = ((const float4*)(fp + 2048))[0];
            float4 b1 = ((const float4*)(fp + 2048))[1];
            float4 a2 = ((const float4*)(fp + 4096))[0];
            float4 b2 = ((const float4*)(fp + 4096))[1];
            float4 a3 = ((const float4*)(fp + 6144))[0];
            float4 b3 = ((const float4*)(fp + 6144))[1];
            float4 a4 = ((const float4*)(fp + 8192))[0];
            float4 b4 = ((const float4*)(fp + 8192))[1];
            acc[0] += ((a0.x + a1.x) + (a2.x + a3.x)) + a4.x;
            acc[1] += ((a0.y + a1.y) + (a2.y + a3.y)) + a4.y;
            acc[2] += ((a0.z + a1.z) + (a2.z + a3.z)) + a4.z;
            acc[3] += ((a0.w + a1.w) + (a2.w + a3.w)) + a4.w;
            acc[4] += ((b0.x + b1.x) + (b2.x + b3.x)) + b4.x;
            acc[5] += ((b0.y + b1.y) + (b2.y + b3.y)) + b4.y;
            acc[6] += ((b0.z + b1.z) + (b2.z + b3.z)) + b4.z;
            acc[7] += ((b0.w + b1.w) + (b2.w + b3.w)) + b4.w;
            fp += 5 * 2048;
        }
    }

#pragma unroll
    for (int e = 0; e < 8; e++) part[g][ct * 8 + e] = acc[e];
    __syncthreads();

    float* dst = ws + WS_MEANS + (arr * 64 + b) * 2048;
    for (int c = t; c < 2048; c += 1024)
        dst[c] = (part[0][c] + part[1][c]) + (part[2][c] + part[3][c]);
}

// ---------------- kernel 3: raw dots q.neg_row + row sumsq ------------------
// grid 1920 = which(2) * b(64) * chunk(15 of 10 rows); block 256 = 4 waves.
// q fragment in 32 registers per lane. bf16 path loads TWO full rows raw
// (8 x 16 B in flight) before converting/accumulating.
__device__ __forceinline__ void dotrow_bf(const uint4* r, const float* qreg,
                                          float& dot, float& nsq) {
#pragma unroll
    for (int it = 0; it < 4; it++) {
        const unsigned short* hs = (const unsigned short*)&r[it];
#pragma unroll
        for (int k = 0; k < 8; k++) {
            float x = bf2f(hs[k]);
            dot += x * qreg[it * 8 + k];
            nsq += x * x;
        }
    }
}

__global__ void k_dots(const void* EA, const void* EB, float* ws) {
    int bf = ((const int*)ws)[0];
    int bi = blockIdx.x;
    int which = bi / 960;
    int rem = bi % 960;
    int b = rem / 15;
    int chunk = rem % 15;
    int lane = threadIdx.x & 63;
    int wid = threadIdx.x >> 6;

    const float* qb = ws + WS_MEANS + ((which == 0 ? 0 : 2) * 64 + b) * 2048;
    float qreg[32];
#pragma unroll
    for (int it = 0; it < 4; it++) {
        const float4* p = (const float4*)(qb + it * 512 + lane * 8);
        float4 a = p[0], c = p[1];
        qreg[it * 8 + 0] = a.x; qreg[it * 8 + 1] = a.y;
        qreg[it * 8 + 2] = a.z; qreg[it * 8 + 3] = a.w;
        qreg[it * 8 + 4] = c.x; qreg[it * 8 + 5] = c.y;
        qreg[it * 8 + 6] = c.z; qreg[it * 8 + 7] = c.w;
    }

    const void* neg = (which == 0) ? EB : EA;
    int e0 = chunk * 10;
    int outb = WS_DOTS + (which * 64 + b) * 150;
    int nsqb = WS_NSQ + (which * 64 + b) * 150;

    if (bf) {
        const unsigned short* np = (const unsigned short*)neg;
        int jA = e0 + wid;          // always < e0+10
        int jB = jA + 4;            // always < e0+10
        int jC = jA + 8;            // valid iff wid < 2 (wave-uniform)
        uint4 rA[4], rB[4];
#pragma unroll
        for (int it = 0; it < 4; it++)
            rA[it] = *(const uint4*)(np + (b * 150 + jA) * 2048 + it * 512 + lane * 8);
#pragma unroll
        for (int it = 0; it < 4; it++)
            rB[it] = *(const uint4*)(np + (b * 150 + jB) * 2048 + it * 512 + lane * 8);
        float dA = 0.f, nA = 0.f, dB = 0.f, nB = 0.f;
        dotrow_bf(rA, qreg, dA, nA);
        dotrow_bf(rB, qreg, dB, nB);
        for (int s = 32; s > 0; s >>= 1) {
            dA += __shfl_down(dA, s); nA += __shfl_down(nA, s);
            dB += __shfl_down(dB, s); nB += __shfl_down(nB, s);
        }
        if (lane == 0) {
            ws[outb + jA] = dA; ws[nsqb + jA] = nA;
            ws[outb + jB] = dB; ws[nsqb + jB] = nB;
        }
        if (jC < e0 + 10) {
            uint4 rC[4];
#pragma unroll
            for (int it = 0; it < 4; it++)
                rC[it] = *(const uint4*)(np + (b * 150 + jC) * 2048 + it * 512 + lane * 8);
            float dC = 0.f, nC = 0.f;
            dotrow_bf(rC, qreg, dC, nC);
            for (int s = 32; s > 0; s >>= 1) {
                dC += __shfl_down(dC, s); nC += __shfl_down(nC, s);
            }
            if (lane == 0) {
                ws[outb + jC] = dC; ws[nsqb + jC] = nC;
            }
        }
    } else {
        for (int j = e0 + wid; j < e0 + 10; j += 4) {
            int base = (b * 150 + j) * 2048;
            float dot = 0.f, nsq = 0.f;
#pragma unroll
            for (int it = 0; it < 4; it++) {
                int off = it * 512 + lane * 8;
                F8 v = ld8(neg, base + off, 0);
#pragma unroll
                for (int k = 0; k < 8; k++) {
                    float x = v.v[k];
                    dot += x * qreg[it * 8 + k];
                    nsq += x * x;
                }
            }
            for (int s = 32; s > 0; s >>= 1) {
                dot += __shfl_down(dot, s);
                nsq += __shfl_down(nsq, s);
            }
            if (lane == 0) {
                ws[outb + j] = dot;
                ws[nsqb + j] = nsq;
            }
        }
    }
}

// ---------------- kernel 4: fused cls + rel + act ---------------------------
// grid 66: block 0 = cls; blocks 1..32 = rel + act-part2; blocks 33..65 = act-part1
__global__ void k_small(const void* vs, const void* label,
                        const void* res, const void* red,
                        const void* a0, const void* a2, float* ws) {
    int bf = ((const int*)ws)[0];
    __shared__ float sbuf[256];
    __shared__ float rowsum[64];
    __shared__ float sa0[64 * 40];
    __shared__ float sa2[64 * 40];
    int t = threadIdx.x;
    int bi = blockIdx.x;

    if (bi == 0) {
        // ---- loss_cls ----
        if (t < 64) {
            float s = 0.f;
            for (int c = 0; c < 20; c++) s += ldf(label, t * 20 + c, bf);
            rowsum[t] = s;
        }
        __syncthreads();
        float local = 0.f;
        for (int i = t; i < 1280; i += 256) {
            int b = i / 20;
            float lab = ldf(label, i, bf) / rowsum[b];
            float v = ldf(vs, i, bf);
            v = fminf(fmaxf(v, EPSF), 1.f - EPSF);
            local += lab * logf(v) + (1.f - lab) * log1pf(-v);
        }
        float s = block_reduce256(local, sbuf);
        if (t == 0) ws[8] = -s / 1280.f;
    } else if (bi <= 32) {
        // ---- loss_rel + act part2 ----
        int base = (bi - 1) * 256 + t;
        int stride = 32 * 256;
        float lrel = 0.f;
        for (int i = base; i < 96000; i += stride) {
            float sv = ldf(res, i, bf);
            float dv = ldf(red, i, bf);
            lrel += (1.f - sv) * (1.f - sv) + dv * dv;
        }
        float s = block_reduce256(lrel, sbuf);
        if (t == 0) atomicAdd(&ws[9], s * (1.f / 96000.f));
        float lact = 0.f;
        for (int i = base; i < 48000; i += stride) {
            float x = ldf(a0, i, bf) - ldf(a2, i, bf);
            lact += x * x;
        }
        s = block_reduce256(lact, sbuf);
        if (t == 0) atomicAdd(&ws[10], s * (0.1f / 64.f));
    } else {
        // ---- act part1: 750x11 windows, sum over batch; LDS staging ----
        int abi = bi - 33;
        int B0 = abi * 256;
        int B1 = min(B0 + 255, 8249);
        int tmin = B0 / 11, tmax = B1 / 11;
        int lo = max(0, tmin - 6);
        int hi = min(749, tmax + 5);
        int ncol = hi - lo + 1;  // <= 36
        int total = 64 * ncol;
        for (int i = t; i < total; i += 256) {
            int b = i / ncol;
            int col = i % ncol;
            sa0[i] = ldf(a0, b * 750 + lo + col, bf);
            sa2[i] = ldf(a2, b * 750 + lo + col, bf);
        }
        __syncthreads();
        int id = B0 + t;
        float val = 0.f;
        if (id < 8250) {
            int tt = id / 11;
            int d = id % 11;
            int c = min(max(tt + d - 6, 0), 749);
            int ct = tt - lo, cc = c - lo;
            float wsum = 0.f, asum = 0.f;
            for (int b = 0; b < 64; b++) {
                float x = sa0[b * ncol + ct];
                float y = sa0[b * ncol + cc];
                wsum += (x - y) * (x - y);
                float p = sa2[b * ncol + ct];
                float q = sa2[b * ncol + cc];
                asum += fabsf(p - q);
            }
            val = __expf(-0.5f * wsum) * (asum * (1.f / 64.f));
        }
        float s = block_reduce256(val, sbuf);
        if (t == 0) atomicAdd(&ws[10], s);
    }
}

// ---------------- kernel 5: NCE norms + logsumexp per (which,b) -------------
// grid 128; block 256
__global__ void k_nce(const void* att, float* ws) {
    int bf = ((const int*)ws)[0];
    __shared__ float sbuf[256];
    int t = threadIdx.x;
    int w = blockIdx.x >> 6;
    int b = blockIdx.x & 63;
    const float* qv = ws + WS_MEANS + ((w == 0 ? 0 : 2) * 64 + b) * 2048;
    const float* kv = ws + WS_MEANS + ((w == 0 ? 1 : 3) * 64 + b) * 2048;
    float p0 = 0.f, p1 = 0.f, p2 = 0.f;
    for (int c = t; c < 2048; c += 256) {
        float qa = qv[c], ka = kv[c];
        p0 += qa * qa; p1 += ka * ka; p2 += qa * ka;
    }
    float nq = block_reduce256(p0, sbuf);
    float nk = block_reduce256(p1, sbuf);
    float dd = block_reduce256(p2, sbuf);
    float invq = rsqrtf(nq);
    float lpos = dd * invq * rsqrtf(nk) * (1.f / T_NCE);
    float lg = -INFINITY;
    if (t < 150) {
        float raw = ws[WS_DOTS + (w * 64 + b) * 150 + t];
        float nn = ws[WS_NSQ + (w * 64 + b) * 150 + t];
        float a = ldf(att, b * 300 + w * 150 + t, bf);
        lg = a * raw * invq * rsqrtf(nn) * (1.f / T_NCE);
    }
    float m = block_reduce_max256(lg, sbuf);
    m = fmaxf(m, lpos);
    float ex = (t < 150) ? expf(lg - m) : 0.f;
    float ssum = block_reduce256(ex, sbuf) + expf(lpos - m);
    if (t == 0) {
        float loss = (m + logf(ssum)) - lpos;  // -log_softmax[0]
        atomicAdd(&ws[11], loss * (1.f / 64.f));
    }
}

// ---------------- kernel 6: final combine -----------------------------------
__global__ void k_out(float* ws, void* out) {
    if (threadIdx.x == 0) {
        int bf = ((const int*)ws)[0];
        float cls = ws[8], rel = ws[9], act = ws[10], snico = ws[11];
        float total = cls + 0.01f * snico + act + 0.1f * rel;
        if (bf) {
            __hip_bfloat16* o = (__hip_bfloat16*)out;
            o[0] = __float2bfloat16(total);
            o[1] = __float2bfloat16(cls);
            o[2] = __float2bfloat16(snico);
            o[3] = __float2bfloat16(act);
            o[4] = __float2bfloat16(rel);
        } else {
            float* o = (float*)out;
            o[0] = total; o[1] = cls; o[2] = snico; o[3] = act; o[4] = rel;
        }
    }
}

extern "C" void kernel_launch(void* const* d_in, const int* in_sizes, int n_in,
                              void* d_out, int out_size, void* d_ws, size_t ws_size,
                              hipStream_t stream) {
    const void* video_scores = d_in[0];
    const void* label = d_in[1];
    const void* HA = d_in[2];
    const void* EA = d_in[3];
    const void* HB = d_in[4];
    const void* EB = d_in[5];
    const void* re_s = d_in[6];
    const void* re_d = d_in[7];
    const void* actioness = d_in[8];
    const void* actioness_2 = d_in[9];
    const void* att = d_in[10];
    float* ws = (float*)d_ws;

    k_zero<<<1, 64, 0, stream>>>(video_scores, ws);
    k_means<<<256, 1024, 0, stream>>>(HA, EA, HB, EB, ws);
    k_dots<<<1920, 256, 0, stream>>>(EA, EB, ws);
    k_small<<<66, 256, 0, stream>>>(video_scores, label, re_s, re_d,
                                    actioness, actioness_2, ws);
    k_nce<<<128, 256, 0, stream>>>(att, ws);
    k_out<<<1, 1, 0, stream>>>(ws, d_out);
}

// Round 5
// 347.811 us; speedup vs baseline: 1.2502x; 1.0027x over previous
//
#include <hip/hip_runtime.h>
#include <hip/hip_bf16.h>
#include <math.h>

#define T_NCE 0.07f
#define EPSF 1e-7f

// ---------------- workspace layout (float units) ----------------
// [0]  : dtype flag (int; 1 = bf16 inputs, 0 = f32 inputs)
// [8]  : acc loss_cls   [9] : acc loss_rel
// [10] : acc loss_act   [11]: acc snico sum
// WS_MEANS : 4*64*2048 per-batch channel SUMS (not means; scale cancels in NCE)
// WS_DOTS  : 2*64*150 raw dots   WS_NSQ : 2*64*150 row sumsq
#define WS_MEANS 32
#define MEANS_N (4 * 64 * 2048)
#define WS_DOTS (WS_MEANS + MEANS_N)
#define WS_NSQ  (WS_DOTS + 2 * 64 * 150)

__device__ __forceinline__ float bf2f(unsigned short h) {
    unsigned int u = ((unsigned int)h) << 16;
    float f;
    __builtin_memcpy(&f, &u, 4);
    return f;
}

__device__ __forceinline__ float ldf(const void* p, int i, int bf) {
    if (bf) return bf2f(((const unsigned short*)p)[i]);
    return ((const float*)p)[i];
}

struct F8 { float v[8]; };

__device__ __forceinline__ F8 ld8(const void* p, int i, int bf) {
    F8 r;
    if (bf) {
        uint4 u = *((const uint4*)((const unsigned short*)p + i));
        const unsigned short* hs = (const unsigned short*)&u;
#pragma unroll
        for (int k = 0; k < 8; k++) r.v[k] = bf2f(hs[k]);
    } else {
        const float4* q = (const float4*)((const float*)p + i);
        float4 a = q[0], b = q[1];
        r.v[0] = a.x; r.v[1] = a.y; r.v[2] = a.z; r.v[3] = a.w;
        r.v[4] = b.x; r.v[5] = b.y; r.v[6] = b.z; r.v[7] = b.w;
    }
    return r;
}

__device__ __forceinline__ float block_reduce256(float v, float* sbuf) {
    int t = threadIdx.x;
    sbuf[t] = v;
    __syncthreads();
    for (int s = 128; s > 0; s >>= 1) {
        if (t < s) sbuf[t] += sbuf[t + s];
        __syncthreads();
    }
    float r = sbuf[0];
    __syncthreads();
    return r;
}

__device__ __forceinline__ float block_reduce_max256(float v, float* sbuf) {
    int t = threadIdx.x;
    sbuf[t] = v;
    __syncthreads();
    for (int s = 128; s > 0; s >>= 1) {
        if (t < s) sbuf[t] = fmaxf(sbuf[t], sbuf[t + s]);
        __syncthreads();
    }
    float r = sbuf[0];
    __syncthreads();
    return r;
}

// ---------------- kernel 1: probe dtype + zero the 4 loss accumulators -----
__global__ void k_zero(const void* video_scores, float* ws) {
    if (threadIdx.x == 0) {
        const unsigned short* u = (const unsigned short*)video_scores;
        int cnt = 0;
        for (int i = 0; i < 64; i++) {
            unsigned short h = u[2 * i];
            int e = (h >> 7) & 0xFF;
            int sgn = (h >> 15) & 1;
            if (!sgn && e >= 90 && e <= 126) cnt++;
        }
        ((int*)ws)[0] = (cnt >= 56) ? 1 : 0;
        ws[8] = 0.f; ws[9] = 0.f; ws[10] = 0.f; ws[11] = 0.f;
    }
}

// ---- consume 5 bf16 rows (uint4 each) into 8 f32 accumulators --------------
__device__ __forceinline__ void acc5bf(float* acc, uint4 r0, uint4 r1, uint4 r2,
                                       uint4 r3, uint4 r4) {
    const unsigned short* h0 = (const unsigned short*)&r0;
    const unsigned short* h1 = (const unsigned short*)&r1;
    const unsigned short* h2 = (const unsigned short*)&r2;
    const unsigned short* h3 = (const unsigned short*)&r3;
    const unsigned short* h4 = (const unsigned short*)&r4;
#pragma unroll
    for (int e = 0; e < 8; e++)
        acc[e] += ((bf2f(h0[e]) + bf2f(h1[e])) +
                   (bf2f(h2[e]) + bf2f(h3[e]))) + bf2f(h4[e]);
}

__device__ __forceinline__ void acc2f(float* acc, float4 a0, float4 b0,
                                      float4 a1, float4 b1) {
    acc[0] += a0.x + a1.x; acc[1] += a0.y + a1.y;
    acc[2] += a0.z + a1.z; acc[3] += a0.w + a1.w;
    acc[4] += b0.x + b1.x; acc[5] += b0.y + b1.y;
    acc[6] += b0.z + b1.z; acc[7] += b0.w + b1.w;
}

// ---------------- kernel 2: per-batch channel sums of HA/EA/HB/EB -----------
// grid 256 = arr(4) * b(64); block 1024 = 4 row-groups x 256 ch-threads.
// SOFTWARE DOUBLE-BUFFER: prologue loads 5 rows; each iteration issues the
// NEXT 5 loads (no consumer until next iter) then consumes the current 5 under
// vmcnt(5). R3's single-set version compiled to VGPR=32: the occupancy-greedy
// allocator serialized load->waitcnt(0)->consume (1.4 TB/s, VALUBusy 1.8%).
// Liveness of 10 uint4 + 8 acc forces ~64+ VGPRs; __launch_bounds__(1024,4)
// (= 16 waves/CU, matching the 1-block/CU grid) lifts the VGPR cap to 128 so
// the allocator doesn't squeeze the pipeline back out.
// Cross-group combine via LDS; plain stores; no atomics.
__global__ __launch_bounds__(1024, 4) void k_means(const void* HA, const void* EA,
                                                   const void* HB, const void* EB,
                                                   float* ws) {
    int bf = ((const int*)ws)[0];
    __shared__ float part[4][2048];
    int bi = blockIdx.x;
    int b = bi & 63;
    int arr = bi >> 6;
    const void* src = (arr == 0) ? HA : (arr == 1) ? EA : (arr == 2) ? HB : EB;
    int t = threadIdx.x;
    int ct = t & 255;
    int g = t >> 8;               // row-group 0..3 (wave-uniform)
    int j0 = g * 40;              // rows [j0, j0+40) for g<3, [120,150) for g=3
    int base = (b * 150 + j0) * 2048 + ct * 8;

    float acc[8];
#pragma unroll
    for (int e = 0; e < 8; e++) acc[e] = 0.f;

    if (bf) {
        int n5 = (g < 3) ? 8 : 6;           // 5-row steps
        const unsigned short* sp = (const unsigned short*)src + base;
        uint4 a0 = *(const uint4*)(sp);
        uint4 a1 = *(const uint4*)(sp + 2048);
        uint4 a2 = *(const uint4*)(sp + 4096);
        uint4 a3 = *(const uint4*)(sp + 6144);
        uint4 a4 = *(const uint4*)(sp + 8192);
        sp += 5 * 2048;
        for (int it = 1; it < n5; it++) {
            uint4 b0 = *(const uint4*)(sp);
            uint4 b1 = *(const uint4*)(sp + 2048);
            uint4 b2 = *(const uint4*)(sp + 4096);
            uint4 b3 = *(const uint4*)(sp + 6144);
            uint4 b4 = *(const uint4*)(sp + 8192);
            sp += 5 * 2048;
            acc5bf(acc, a0, a1, a2, a3, a4);
            a0 = b0; a1 = b1; a2 = b2; a3 = b3; a4 = b4;
        }
        acc5bf(acc, a0, a1, a2, a3, a4);
    } else {
        int n2 = (g < 3) ? 20 : 15;         // 2-row steps
        const float* fp = (const float*)src + base;
        float4 a0 = ((const float4*)(fp))[0];
        float4 b0 = ((const float4*)(fp))[1];
        float4 a1 = ((const float4*)(fp + 2048))[0];
        float4 b1 = ((const float4*)(fp + 2048))[1];
        fp += 2 * 2048;
        for (int it = 1; it < n2; it++) {
            float4 c0 = ((const float4*)(fp))[0];
            float4 d0 = ((const float4*)(fp))[1];
            float4 c1 = ((const float4*)(fp + 2048))[0];
            float4 d1 = ((const float4*)(fp + 2048))[1];
            fp += 2 * 2048;
            acc2f(acc, a0, b0, a1, b1);
            a0 = c0; b0 = d0; a1 = c1; b1 = d1;
        }
        acc2f(acc, a0, b0, a1, b1);
    }

#pragma unroll
    for (int e = 0; e < 8; e++) part[g][ct * 8 + e] = acc[e];
    __syncthreads();

    float* dst = ws + WS_MEANS + (arr * 64 + b) * 2048;
    for (int c = t; c < 2048; c += 1024)
        dst[c] = (part[0][c] + part[1][c]) + (part[2][c] + part[3][c]);
}

// ---------------- kernel 3: raw dots q.neg_row + row sumsq ------------------
// grid 1920 = which(2) * b(64) * chunk(15 of 10 rows); block 256 = 4 waves.
// q fragment in 32 registers per lane. bf16 path loads TWO full rows raw
// (8 x 16 B in flight) before converting/accumulating.
__device__ __forceinline__ void dotrow_bf(const uint4* r, const float* qreg,
                                          float& dot, float& nsq) {
#pragma unroll
    for (int it = 0; it < 4; it++) {
        const unsigned short* hs = (const unsigned short*)&r[it];
#pragma unroll
        for (int k = 0; k < 8; k++) {
            float x = bf2f(hs[k]);
            dot += x * qreg[it * 8 + k];
            nsq += x * x;
        }
    }
}

__global__ void k_dots(const void* EA, const void* EB, float* ws) {
    int bf = ((const int*)ws)[0];
    int bi = blockIdx.x;
    int which = bi / 960;
    int rem = bi % 960;
    int b = rem / 15;
    int chunk = rem % 15;
    int lane = threadIdx.x & 63;
    int wid = threadIdx.x >> 6;

    const float* qb = ws + WS_MEANS + ((which == 0 ? 0 : 2) * 64 + b) * 2048;
    float qreg[32];
#pragma unroll
    for (int it = 0; it < 4; it++) {
        const float4* p = (const float4*)(qb + it * 512 + lane * 8);
        float4 a = p[0], c = p[1];
        qreg[it * 8 + 0] = a.x; qreg[it * 8 + 1] = a.y;
        qreg[it * 8 + 2] = a.z; qreg[it * 8 + 3] = a.w;
        qreg[it * 8 + 4] = c.x; qreg[it * 8 + 5] = c.y;
        qreg[it * 8 + 6] = c.z; qreg[it * 8 + 7] = c.w;
    }

    const void* neg = (which == 0) ? EB : EA;
    int e0 = chunk * 10;
    int outb = WS_DOTS + (which * 64 + b) * 150;
    int nsqb = WS_NSQ + (which * 64 + b) * 150;

    if (bf) {
        const unsigned short* np = (const unsigned short*)neg;
        int jA = e0 + wid;          // always < e0+10
        int jB = jA + 4;            // always < e0+10
        int jC = jA + 8;            // valid iff wid < 2 (wave-uniform)
        uint4 rA[4], rB[4];
#pragma unroll
        for (int it = 0; it < 4; it++)
            rA[it] = *(const uint4*)(np + (b * 150 + jA) * 2048 + it * 512 + lane * 8);
#pragma unroll
        for (int it = 0; it < 4; it++)
            rB[it] = *(const uint4*)(np + (b * 150 + jB) * 2048 + it * 512 + lane * 8);
        float dA = 0.f, nA = 0.f, dB = 0.f, nB = 0.f;
        dotrow_bf(rA, qreg, dA, nA);
        dotrow_bf(rB, qreg, dB, nB);
        for (int s = 32; s > 0; s >>= 1) {
            dA += __shfl_down(dA, s); nA += __shfl_down(nA, s);
            dB += __shfl_down(dB, s); nB += __shfl_down(nB, s);
        }
        if (lane == 0) {
            ws[outb + jA] = dA; ws[nsqb + jA] = nA;
            ws[outb + jB] = dB; ws[nsqb + jB] = nB;
        }
        if (jC < e0 + 10) {
            uint4 rC[4];
#pragma unroll
            for (int it = 0; it < 4; it++)
                rC[it] = *(const uint4*)(np + (b * 150 + jC) * 2048 + it * 512 + lane * 8);
            float dC = 0.f, nC = 0.f;
            dotrow_bf(rC, qreg, dC, nC);
            for (int s = 32; s > 0; s >>= 1) {
                dC += __shfl_down(dC, s); nC += __shfl_down(nC, s);
            }
            if (lane == 0) {
                ws[outb + jC] = dC; ws[nsqb + jC] = nC;
            }
        }
    } else {
        for (int j = e0 + wid; j < e0 + 10; j += 4) {
            int base = (b * 150 + j) * 2048;
            float dot = 0.f, nsq = 0.f;
#pragma unroll
            for (int it = 0; it < 4; it++) {
                int off = it * 512 + lane * 8;
                F8 v = ld8(neg, base + off, 0);
#pragma unroll
                for (int k = 0; k < 8; k++) {
                    float x = v.v[k];
                    dot += x * qreg[it * 8 + k];
                    nsq += x * x;
                }
            }
            for (int s = 32; s > 0; s >>= 1) {
                dot += __shfl_down(dot, s);
                nsq += __shfl_down(nsq, s);
            }
            if (lane == 0) {
                ws[outb + j] = dot;
                ws[nsqb + j] = nsq;
            }
        }
    }
}

// ---------------- kernel 4: fused cls + rel + act ---------------------------
// grid 66: block 0 = cls; blocks 1..32 = rel + act-part2; blocks 33..65 = act-part1
__global__ void k_small(const void* vs, const void* label,
                        const void* res, const void* red,
                        const void* a0, const void* a2, float* ws) {
    int bf = ((const int*)ws)[0];
    __shared__ float sbuf[256];
    __shared__ float rowsum[64];
    __shared__ float sa0[64 * 40];
    __shared__ float sa2[64 * 40];
    int t = threadIdx.x;
    int bi = blockIdx.x;

    if (bi == 0) {
        // ---- loss_cls ----
        if (t < 64) {
            float s = 0.f;
            for (int c = 0; c < 20; c++) s += ldf(label, t * 20 + c, bf);
            rowsum[t] = s;
        }
        __syncthreads();
        float local = 0.f;
        for (int i = t; i < 1280; i += 256) {
            int b = i / 20;
            float lab = ldf(label, i, bf) / rowsum[b];
            float v = ldf(vs, i, bf);
            v = fminf(fmaxf(v, EPSF), 1.f - EPSF);
            local += lab * logf(v) + (1.f - lab) * log1pf(-v);
        }
        float s = block_reduce256(local, sbuf);
        if (t == 0) ws[8] = -s / 1280.f;
    } else if (bi <= 32) {
        // ---- loss_rel + act part2 ----
        int base = (bi - 1) * 256 + t;
        int stride = 32 * 256;
        float lrel = 0.f;
        for (int i = base; i < 96000; i += stride) {
            float sv = ldf(res, i, bf);
            float dv = ldf(red, i, bf);
            lrel += (1.f - sv) * (1.f - sv) + dv * dv;
        }
        float s = block_reduce256(lrel, sbuf);
        if (t == 0) atomicAdd(&ws[9], s * (1.f / 96000.f));
        float lact = 0.f;
        for (int i = base; i < 48000; i += stride) {
            float x = ldf(a0, i, bf) - ldf(a2, i, bf);
            lact += x * x;
        }
        s = block_reduce256(lact, sbuf);
        if (t == 0) atomicAdd(&ws[10], s * (0.1f / 64.f));
    } else {
        // ---- act part1: 750x11 windows, sum over batch; LDS staging ----
        int abi = bi - 33;
        int B0 = abi * 256;
        int B1 = min(B0 + 255, 8249);
        int tmin = B0 / 11, tmax = B1 / 11;
        int lo = max(0, tmin - 6);
        int hi = min(749, tmax + 5);
        int ncol = hi - lo + 1;  // <= 36
        int total = 64 * ncol;
        for (int i = t; i < total; i += 256) {
            int b = i / ncol;
            int col = i % ncol;
            sa0[i] = ldf(a0, b * 750 + lo + col, bf);
            sa2[i] = ldf(a2, b * 750 + lo + col, bf);
        }
        __syncthreads();
        int id = B0 + t;
        float val = 0.f;
        if (id < 8250) {
            int tt = id / 11;
            int d = id % 11;
            int c = min(max(tt + d - 6, 0), 749);
            int ct = tt - lo, cc = c - lo;
            float wsum = 0.f, asum = 0.f;
            for (int b = 0; b < 64; b++) {
                float x = sa0[b * ncol + ct];
                float y = sa0[b * ncol + cc];
                wsum += (x - y) * (x - y);
                float p = sa2[b * ncol + ct];
                float q = sa2[b * ncol + cc];
                asum += fabsf(p - q);
            }
            val = __expf(-0.5f * wsum) * (asum * (1.f / 64.f));
        }
        float s = block_reduce256(val, sbuf);
        if (t == 0) atomicAdd(&ws[10], s);
    }
}

// ---------------- kernel 5: NCE norms + logsumexp per (which,b) -------------
// grid 128; block 256
__global__ void k_nce(const void* att, float* ws) {
    int bf = ((const int*)ws)[0];
    __shared__ float sbuf[256];
    int t = threadIdx.x;
    int w = blockIdx.x >> 6;
    int b = blockIdx.x & 63;
    const float* qv = ws + WS_MEANS + ((w == 0 ? 0 : 2) * 64 + b) * 2048;
    const float* kv = ws + WS_MEANS + ((w == 0 ? 1 : 3) * 64 + b) * 2048;
    float p0 = 0.f, p1 = 0.f, p2 = 0.f;
    for (int c = t; c < 2048; c += 256) {
        float qa = qv[c], ka = kv[c];
        p0 += qa * qa; p1 += ka * ka; p2 += qa * ka;
    }
    float nq = block_reduce256(p0, sbuf);
    float nk = block_reduce256(p1, sbuf);
    float dd = block_reduce256(p2, sbuf);
    float invq = rsqrtf(nq);
    float lpos = dd * invq * rsqrtf(nk) * (1.f / T_NCE);
    float lg = -INFINITY;
    if (t < 150) {
        float raw = ws[WS_DOTS + (w * 64 + b) * 150 + t];
        float nn = ws[WS_NSQ + (w * 64 + b) * 150 + t];
        float a = ldf(att, b * 300 + w * 150 + t, bf);
        lg = a * raw * invq * rsqrtf(nn) * (1.f / T_NCE);
    }
    float m = block_reduce_max256(lg, sbuf);
    m = fmaxf(m, lpos);
    float ex = (t < 150) ? expf(lg - m) : 0.f;
    float ssum = block_reduce256(ex, sbuf) + expf(lpos - m);
    if (t == 0) {
        float loss = (m + logf(ssum)) - lpos;  // -log_softmax[0]
        atomicAdd(&ws[11], loss * (1.f / 64.f));
    }
}

// ---------------- kernel 6: final combine -----------------------------------
__global__ void k_out(float* ws, void* out) {
    if (threadIdx.x == 0) {
        int bf = ((const int*)ws)[0];
        float cls = ws[8], rel = ws[9], act = ws[10], snico = ws[11];
        float total = cls + 0.01f * snico + act + 0.1f * rel;
        if (bf) {
            __hip_bfloat16* o = (__hip_bfloat16*)out;
            o[0] = __float2bfloat16(total);
            o[1] = __float2bfloat16(cls);
            o[2] = __float2bfloat16(snico);
            o[3] = __float2bfloat16(act);
            o[4] = __float2bfloat16(rel);
        } else {
            float* o = (float*)out;
            o[0] = total; o[1] = cls; o[2] = snico; o[3] = act; o[4] = rel;
        }
    }
}

extern "C" void kernel_launch(void* const* d_in, const int* in_sizes, int n_in,
                              void* d_out, int out_size, void* d_ws, size_t ws_size,
                              hipStream_t stream) {
    const void* video_scores = d_in[0];
    const void* label = d_in[1];
    const void* HA = d_in[2];
    const void* EA = d_in[3];
    const void* HB = d_in[4];
    const void* EB = d_in[5];
    const void* re_s = d_in[6];
    const void* re_d = d_in[7];
    const void* actioness = d_in[8];
    const void* actioness_2 = d_in[9];
    const void* att = d_in[10];
    float* ws = (float*)d_ws;

    k_zero<<<1, 64, 0, stream>>>(video_scores, ws);
    k_means<<<256, 1024, 0, stream>>>(HA, EA, HB, EB, ws);
    k_dots<<<1920, 256, 0, stream>>>(EA, EB, ws);
    k_small<<<66, 256, 0, stream>>>(video_scores, label, re_s, re_d,
                                    actioness, actioness_2, ws);
    k_nce<<<128, 256, 0, stream>>>(att, ws);
    k_out<<<1, 1, 0, stream>>>(ws, d_out);
}